// Round 1
// 605.540 us; speedup vs baseline: 1.0221x; 1.0221x over previous
//
#include <hip/hip_runtime.h>

// VGAE on MI355X — round 3: decode de-thrash.
//   - k_decode: single fragment load per k-chunk feeding 3 MFMAs (hh+hl+lh),
//     operand-swapped MFMA so the C-fragment is row-major per lane ->
//     coalesced float4 stores, and NON-TEMPORAL stores so the 400 MB output
//     stream does not evict the L2-resident zh/zl (2.6 MB).
//   - k_zsplit fused into k_gemm2 (LDS exchange of mean/lstd halves).
//   - zh/zl pad-row zeroing folded into k_init.
// Pipeline:
//   deg/cnt (atomic) -> dis=rsqrt -> CSR build (scan + fill, norm inline)
//   hw1 = x@W1                                   (f32 LDS GEMM)
//   h    = dis^2*hw1 + b1 + gather(norm*hw1)     (CSR, no atomics)
//   hagg = dis^2*relu(h) + gather(norm*relu(h))
//   zh,zl = bf16-split(hagg@[W2|W3] + b + noise*exp(.))  (fused, padded rows)
//   out = sigmoid(z@z^T) via 3-term bf16 MFMA: zh*zh + zh*zl + zl*zh
// d_ws: dis + zh + zl (~2.6 MB). Everything else (hw1/h/hagg/CSR) lives in
// d_out's 400 MB; all dead before decode overwrites d_out.

#define Nn 10000
#define Np 10112          // 79*128, padded rows for decode
#define NpK (Np * 64)

typedef short short8 __attribute__((ext_vector_type(8)));
typedef float f32x4 __attribute__((ext_vector_type(4)));
typedef unsigned short ushort4e __attribute__((ext_vector_type(4)));

static __device__ __forceinline__ float sigmoidf(float v) {
  // approx rcp is plenty for the 4e-3 abs tolerance
  return __builtin_amdgcn_rcpf(1.0f + __expf(-v));
}
static __device__ __forceinline__ unsigned short f32_to_bf16(float f) {
  unsigned int u = __float_as_uint(f);
  unsigned int r = (u + 0x7FFF + ((u >> 16) & 1)) >> 16;  // RNE
  return (unsigned short)r;
}
static __device__ __forceinline__ float bf16_to_f32(unsigned short s) {
  return __uint_as_float(((unsigned int)s) << 16);
}

// deg=1 (self loop), cnt=0; also zero zh/zl pad rows (rows Nn..Np)
__global__ void k_init(float* __restrict__ deg, int* __restrict__ cnt, int n,
                       unsigned short* __restrict__ zh, unsigned short* __restrict__ zl) {
  int i = blockIdx.x * 256 + threadIdx.x;
  if (i < n) { deg[i] = 1.0f; cnt[i] = 0; }
  if (i < (Np - Nn) * 64) { zh[Nn * 64 + i] = 0; zl[Nn * 64 + i] = 0; }
}

__global__ void k_edge_pre(const int* __restrict__ col, const float* __restrict__ ew,
                           float* __restrict__ deg, int* __restrict__ cnt, int E) {
  int e = blockIdx.x * 256 + threadIdx.x;
  if (e < E) { int c = col[e]; atomicAdd(&deg[c], ew[e]); atomicAdd(&cnt[c], 1); }
}

__global__ void k_dis(float* __restrict__ deg, int n) {
  int i = blockIdx.x * 256 + threadIdx.x;
  if (i < n) { float d = deg[i]; deg[i] = (d > 0.0f) ? rsqrtf(d) : 0.0f; }
}

// single-block exclusive scan of cnt[0..n) -> ofs[0..n], plus copy into ofs2
__global__ __launch_bounds__(256) void k_scan(const int* __restrict__ cnt,
                                              int* __restrict__ ofs, int* __restrict__ ofs2,
                                              int n) {
  __shared__ int partial[256];
  const int t = threadIdx.x;
  const int CH = (n + 255) / 256;
  const int start = t * CH;
  int local = 0;
  for (int j = 0; j < CH; ++j) {
    int idx = start + j;
    if (idx < n) local += cnt[idx];
  }
  partial[t] = local;
  __syncthreads();
  for (int off = 1; off < 256; off <<= 1) {
    int x = (t >= off) ? partial[t - off] : 0;
    __syncthreads();
    partial[t] += x;
    __syncthreads();
  }
  int run = partial[t] - local;  // exclusive prefix
  for (int j = 0; j < CH; ++j) {
    int idx = start + j;
    if (idx < n) {
      ofs[idx] = run; ofs2[idx] = run;
      run += cnt[idx];
    }
  }
  if (t == 255) { ofs[n] = run; ofs2[n] = run; }
}

// place edges: csr_src[p]=row, csr_w[p]=dis[row]*ew*dis[col]
__global__ void k_fill(const int* __restrict__ row, const int* __restrict__ col,
                       const float* __restrict__ ew, const float* __restrict__ dis,
                       int* __restrict__ ofs2, int* __restrict__ csr_src,
                       float* __restrict__ csr_w, int E) {
  int e = blockIdx.x * 256 + threadIdx.x;
  if (e < E) {
    int r = row[e], c = col[e];
    int p = atomicAdd(&ofs2[c], 1);
    csr_src[p] = r;
    csr_w[p] = dis[r] * ew[e] * dis[c];
  }
}

// hw1 = x[10000,256] @ W1[256,128]
__global__ __launch_bounds__(256) void k_gemm1(const float* __restrict__ x,
                                               const float* __restrict__ W1,
                                               float* __restrict__ hw1) {
  __shared__ float xs[16][68];
  __shared__ float ws[64][128];
  const int tid = threadIdx.x;
  const int row0 = blockIdx.x * 16;
  const int j0 = (tid & 31) * 4;
  const int r0 = (tid >> 5) * 2;
  const int lr = tid >> 4, lk = tid & 15;
  float acc0[4] = {0, 0, 0, 0}, acc1[4] = {0, 0, 0, 0};
  for (int k0 = 0; k0 < 256; k0 += 64) {
    *(float4*)&xs[lr][lk * 4] = *(const float4*)&x[(row0 + lr) * 256 + k0 + lk * 4];
#pragma unroll
    for (int it = 0; it < 8; ++it) {
      int idx4 = tid + it * 256;
      int kk = idx4 >> 5, jq = idx4 & 31;
      *(float4*)&ws[kk][jq * 4] = *(const float4*)&W1[(k0 + kk) * 128 + jq * 4];
    }
    __syncthreads();
#pragma unroll 8
    for (int kk = 0; kk < 64; ++kk) {
      float a0 = xs[r0][kk], a1 = xs[r0 + 1][kk];
      float4 w = *(const float4*)&ws[kk][j0];
      acc0[0] += a0 * w.x; acc0[1] += a0 * w.y; acc0[2] += a0 * w.z; acc0[3] += a0 * w.w;
      acc1[0] += a1 * w.x; acc1[1] += a1 * w.y; acc1[2] += a1 * w.z; acc1[3] += a1 * w.w;
    }
    __syncthreads();
  }
  *(float4*)&hw1[(row0 + r0) * 128 + j0] = make_float4(acc0[0], acc0[1], acc0[2], acc0[3]);
  *(float4*)&hw1[(row0 + r0 + 1) * 128 + j0] = make_float4(acc1[0], acc1[1], acc1[2], acc1[3]);
}

// CSR aggregation, 4 nodes/block (1 wave each), float2 per lane.
// mode 0: out[i] = d^2*feat[i] + b + sum w*feat[src]
// mode 1: out[i] = d^2*relu(feat[i]) + sum w*relu(feat[src])
__global__ __launch_bounds__(256) void k_agg(const int* __restrict__ ofs,
                                             const int* __restrict__ csr_src,
                                             const float* __restrict__ csr_w,
                                             const float* __restrict__ feat,
                                             const float* __restrict__ dis,
                                             const float* __restrict__ b,
                                             float* __restrict__ out, int n, int relu_in) {
  int node = blockIdx.x * 4 + (threadIdx.x >> 6);
  if (node >= n) return;
  int f2 = threadIdx.x & 63;
  const float2* featv = (const float2*)feat;
  int s = ofs[node], e = ofs[node + 1];
  float d = dis[node];
  float2 self = featv[node * 64 + f2];
  float2 acc;
  if (relu_in) {
    acc.x = d * d * fmaxf(self.x, 0.0f);
    acc.y = d * d * fmaxf(self.y, 0.0f);
  } else {
    float2 bb = ((const float2*)b)[f2];
    acc.x = d * d * self.x + bb.x;
    acc.y = d * d * self.y + bb.y;
  }
  for (int j = s; j < e; ++j) {
    int r = csr_src[j];
    float wt = csr_w[j];
    float2 v = featv[r * 64 + f2];
    if (relu_in) { v.x = fmaxf(v.x, 0.0f); v.y = fmaxf(v.y, 0.0f); }
    acc.x += wt * v.x;
    acc.y += wt * v.y;
  }
  ((float2*)out)[node * 64 + f2] = acc;
}

// Fused: [mean|lstd] = hagg[10000,128] @ [W2|W3][128,64] + [b2|b3], then
// z = mean + noise*exp(lstd), bf16 hi/lo split written straight to zh/zl.
__global__ __launch_bounds__(256) void k_gemm2z(const float* __restrict__ hagg,
                                                const float* __restrict__ W2, const float* __restrict__ W3,
                                                const float* __restrict__ b2, const float* __restrict__ b3,
                                                const float* __restrict__ noise,
                                                unsigned short* __restrict__ zh,
                                                unsigned short* __restrict__ zl) {
  __shared__ float xs[16][68];
  __shared__ float ws[64][128];
  __shared__ float zs[16][128];   // [mean | lstd] staging for the fusion
  const int tid = threadIdx.x;
  const int row0 = blockIdx.x * 16;
  const int j0 = (tid & 31) * 4;
  const int r0 = (tid >> 5) * 2;
  const int lr = tid >> 4, lk = tid & 15;
  float acc0[4] = {0, 0, 0, 0}, acc1[4] = {0, 0, 0, 0};
  for (int k0 = 0; k0 < 128; k0 += 64) {
    *(float4*)&xs[lr][lk * 4] = *(const float4*)&hagg[(row0 + lr) * 128 + k0 + lk * 4];
#pragma unroll
    for (int it = 0; it < 8; ++it) {
      int idx4 = tid + it * 256;
      int kk = idx4 >> 5, jq = idx4 & 31;
      int j = jq * 4;
      float4 wv;
      if (j < 64) wv = *(const float4*)&W2[(k0 + kk) * 64 + j];
      else        wv = *(const float4*)&W3[(k0 + kk) * 64 + (j - 64)];
      *(float4*)&ws[kk][j] = wv;
    }
    __syncthreads();
#pragma unroll 8
    for (int kk = 0; kk < 64; ++kk) {
      float a0 = xs[r0][kk], a1 = xs[r0 + 1][kk];
      float4 w = *(const float4*)&ws[kk][j0];
      acc0[0] += a0 * w.x; acc0[1] += a0 * w.y; acc0[2] += a0 * w.z; acc0[3] += a0 * w.w;
      acc1[0] += a1 * w.x; acc1[1] += a1 * w.y; acc1[2] += a1 * w.z; acc1[3] += a1 * w.w;
    }
    __syncthreads();
  }
  {
    float4 bb = (j0 < 64) ? *(const float4*)&b2[j0] : *(const float4*)&b3[j0 - 64];
    zs[r0][j0 + 0] = acc0[0] + bb.x; zs[r0][j0 + 1] = acc0[1] + bb.y;
    zs[r0][j0 + 2] = acc0[2] + bb.z; zs[r0][j0 + 3] = acc0[3] + bb.w;
    zs[r0 + 1][j0 + 0] = acc1[0] + bb.x; zs[r0 + 1][j0 + 1] = acc1[1] + bb.y;
    zs[r0 + 1][j0 + 2] = acc1[2] + bb.z; zs[r0 + 1][j0 + 3] = acc1[3] + bb.w;
  }
  __syncthreads();
  // reparam + bf16 split: thread -> row r = tid>>4, cols jj..jj+3
  {
    const int r = tid >> 4;
    const int jj = (tid & 15) * 4;
    float4 mn = *(const float4*)&zs[r][jj];
    float4 ls = *(const float4*)&zs[r][64 + jj];
    float4 nz = *(const float4*)&noise[(row0 + r) * 64 + jj];
    float z0 = mn.x + nz.x * __expf(ls.x);
    float z1 = mn.y + nz.y * __expf(ls.y);
    float z2 = mn.z + nz.z * __expf(ls.z);
    float z3 = mn.w + nz.w * __expf(ls.w);
    ushort4e h, l;
    h[0] = f32_to_bf16(z0); l[0] = f32_to_bf16(z0 - bf16_to_f32(h[0]));
    h[1] = f32_to_bf16(z1); l[1] = f32_to_bf16(z1 - bf16_to_f32(h[1]));
    h[2] = f32_to_bf16(z2); l[2] = f32_to_bf16(z2 - bf16_to_f32(h[2]));
    h[3] = f32_to_bf16(z3); l[3] = f32_to_bf16(z3 - bf16_to_f32(h[3]));
    *(ushort4e*)&zh[(row0 + r) * 64 + jj] = h;
    *(ushort4e*)&zl[(row0 + r) * 64 + jj] = l;
  }
}

// out = sigmoid(z@z^T), 128x128 tile / 4 waves, each wave 64x64.
// Operand-swapped MFMA: acc = mfma(colfrag, rowfrag) computes the transposed
// C-fragment, so each lane holds 4 consecutive COLUMNS of one row ->
// coalesced float4 stores. One fragment load per k-chunk feeds all 3 split
// terms (hh, hl, lh). Stores are non-temporal so the 400 MB output stream
// does not evict zh/zl (2.6 MB, L2-resident) — that eviction was the
// hypothesized ~400 us of L3/HBM re-fetch.
__global__ __launch_bounds__(256) void k_decode(const unsigned short* __restrict__ zh,
                                                const unsigned short* __restrict__ zl,
                                                float* __restrict__ out, int n) {
  const int tid = threadIdx.x;
  const int wave = tid >> 6, lane = tid & 63;
  const int rows0 = blockIdx.y * 128 + (wave >> 1) * 64;
  const int cols0 = blockIdx.x * 128 + (wave & 1) * 64;
  const int lrow = lane & 15;   // fragment row/col within 16-tile
  const int quad = lane >> 4;   // k = quad*8 + t
  f32x4 acc[4][4];
#pragma unroll
  for (int m = 0; m < 4; ++m)
#pragma unroll
    for (int nn = 0; nn < 4; ++nn) acc[m][nn] = (f32x4){0.0f, 0.0f, 0.0f, 0.0f};

#pragma unroll
  for (int kc = 0; kc < 64; kc += 32) {
    const int ko = kc + quad * 8;
    short8 rh[4], rl[4], ch[4], cl[4];
#pragma unroll
    for (int m = 0; m < 4; ++m) {
      rh[m] = *(const short8*)&zh[(rows0 + m * 16 + lrow) * 64 + ko];
      rl[m] = *(const short8*)&zl[(rows0 + m * 16 + lrow) * 64 + ko];
    }
#pragma unroll
    for (int nn = 0; nn < 4; ++nn) {
      ch[nn] = *(const short8*)&zh[(cols0 + nn * 16 + lrow) * 64 + ko];
      cl[nn] = *(const short8*)&zl[(cols0 + nn * 16 + lrow) * 64 + ko];
    }
#pragma unroll
    for (int m = 0; m < 4; ++m)
#pragma unroll
      for (int nn = 0; nn < 4; ++nn) {
        // transposed tiles: D~[i][j] = sum_k Zc[i][k]*Zr[j][k]
        acc[m][nn] = __builtin_amdgcn_mfma_f32_16x16x32_bf16(ch[nn], rh[m], acc[m][nn], 0, 0, 0);
        acc[m][nn] = __builtin_amdgcn_mfma_f32_16x16x32_bf16(cl[nn], rh[m], acc[m][nn], 0, 0, 0);
        acc[m][nn] = __builtin_amdgcn_mfma_f32_16x16x32_bf16(ch[nn], rl[m], acc[m][nn], 0, 0, 0);
      }
  }

  // transposed C layout: lane holds row (rows0+m*16+lrow), cols quad*4+r
#pragma unroll
  for (int m = 0; m < 4; ++m) {
    int gr = rows0 + m * 16 + lrow;
    if (gr >= n) continue;
#pragma unroll
    for (int nn = 0; nn < 4; ++nn) {
      int c0 = cols0 + nn * 16 + quad * 4;
      if (c0 >= n) continue;  // n % 4 == 0 -> chunk fully in or out
      f32x4 v;
      v[0] = sigmoidf(acc[m][nn][0]);
      v[1] = sigmoidf(acc[m][nn][1]);
      v[2] = sigmoidf(acc[m][nn][2]);
      v[3] = sigmoidf(acc[m][nn][3]);
      __builtin_nontemporal_store(v, (f32x4*)&out[(size_t)gr * n + c0]);
    }
  }
}

extern "C" void kernel_launch(void* const* d_in, const int* in_sizes, int n_in,
                              void* d_out, int out_size, void* d_ws, size_t ws_size,
                              hipStream_t stream) {
  const float* x     = (const float*)d_in[0];
  const int*   ei    = (const int*)d_in[1];
  const float* ew    = (const float*)d_in[2];
  const float* noise = (const float*)d_in[3];
  const float* W1    = (const float*)d_in[4];
  const float* b1    = (const float*)d_in[5];
  const float* W2    = (const float*)d_in[6];
  const float* b2    = (const float*)d_in[7];
  const float* W3    = (const float*)d_in[8];
  const float* b3    = (const float*)d_in[9];
  const int E = in_sizes[2];
  const int n = Nn;
  const int* row = ei;
  const int* col = ei + E;

  // d_ws: dis (40 KB) + zh + zl (2.6 MB)
  float* dis = (float*)d_ws;
  unsigned short* zh = (unsigned short*)((char*)d_ws + 10240 * 4);
  unsigned short* zl = zh + NpK;

  // big scratch in d_out (all dead before k_decode rewrites d_out)
  float* S    = (float*)d_out;
  float* hw1  = S;                         // n*128
  float* h    = S + 1310720;               // n*128
  float* hagg = S + 2621440;               // n*128
  float* csr_w  = S + 5242880;             // E
  int* csr_src  = (int*)(S + 5402880);     // E
  int* ofs      = (int*)(S + 5562880);     // n+1
  int* ofs2     = (int*)(S + 5572896);     // n+1
  int* cnt      = (int*)(S + 5582912);     // n

  k_init<<<(n + 255) / 256, 256, 0, stream>>>(dis, cnt, n, zh, zl);
  k_edge_pre<<<(E + 255) / 256, 256, 0, stream>>>(col, ew, dis, cnt, E);
  k_dis<<<(n + 255) / 256, 256, 0, stream>>>(dis, n);
  k_scan<<<1, 256, 0, stream>>>(cnt, ofs, ofs2, n);
  k_fill<<<(E + 255) / 256, 256, 0, stream>>>(row, col, ew, dis, ofs2, csr_src, csr_w, E);

  k_gemm1<<<n / 16, 256, 0, stream>>>(x, W1, hw1);
  k_agg<<<(n + 3) / 4, 256, 0, stream>>>(ofs, csr_src, csr_w, hw1, dis, b1, h, n, 0);
  k_agg<<<(n + 3) / 4, 256, 0, stream>>>(ofs, csr_src, csr_w, h, dis, b1, hagg, n, 1);

  k_gemm2z<<<n / 16, 256, 0, stream>>>(hagg, W2, W3, b2, b3, noise, zh, zl);

  dim3 g((n + 127) / 128, (n + 127) / 128);
  k_decode<<<g, 256, 0, stream>>>(zh, zl, (float*)d_out, n);
}

// Round 2
// 575.442 us; speedup vs baseline: 1.0756x; 1.0523x over previous
//
#include <hip/hip_runtime.h>

// VGAE on MI355X — round 4: decode made cache-independent.
//   - k_decode: zh/zl row+col tiles staged in LDS (64 KB/block, XOR-swizzled
//     chunk^=row&7 -> 2-way ds_read_b128 conflicts = free). Fragment global
//     traffic = exactly one touch per block; store-stream eviction of z is
//     irrelevant. Stores back to REGULAR (L2 write-allocate merges the 64 B
//     half-line segments into full lines; nt prevented that merge).
//   - k_agg: agg1 emits relu(h) directly; agg2 drops per-edge fmax; gather
//     loop explicitly 2-deep software-pipelined.
// Pipeline:
//   deg/cnt (atomic) -> dis=rsqrt -> CSR build (scan + fill, norm inline)
//   hw1 = x@W1                                   (f32 LDS GEMM)
//   hrelu = relu(dis^2*hw1 + b1 + gather(norm*hw1))
//   hagg  = dis^2*hrelu + gather(norm*hrelu)
//   zh,zl = bf16-split(hagg@[W2|W3] + b + noise*exp(.))  (fused, padded rows)
//   out = sigmoid(z@z^T) via 3-term bf16 MFMA: zh*zh + zh*zl + zl*zh
// d_ws: dis + zh + zl (~2.6 MB). Everything else (hw1/h/hagg/CSR) lives in
// d_out's 400 MB; all dead before decode overwrites d_out.

#define Nn 10000
#define Np 10112          // 79*128, padded rows for decode
#define NpK (Np * 64)

typedef short short8 __attribute__((ext_vector_type(8)));
typedef float f32x4 __attribute__((ext_vector_type(4)));
typedef unsigned short ushort4e __attribute__((ext_vector_type(4)));

static __device__ __forceinline__ float sigmoidf(float v) {
  return __builtin_amdgcn_rcpf(1.0f + __expf(-v));
}
static __device__ __forceinline__ unsigned short f32_to_bf16(float f) {
  unsigned int u = __float_as_uint(f);
  unsigned int r = (u + 0x7FFF + ((u >> 16) & 1)) >> 16;  // RNE
  return (unsigned short)r;
}
static __device__ __forceinline__ float bf16_to_f32(unsigned short s) {
  return __uint_as_float(((unsigned int)s) << 16);
}

// deg=1 (self loop), cnt=0; also zero zh/zl pad rows (rows Nn..Np)
__global__ void k_init(float* __restrict__ deg, int* __restrict__ cnt, int n,
                       unsigned short* __restrict__ zh, unsigned short* __restrict__ zl) {
  int i = blockIdx.x * 256 + threadIdx.x;
  if (i < n) { deg[i] = 1.0f; cnt[i] = 0; }
  if (i < (Np - Nn) * 64) { zh[Nn * 64 + i] = 0; zl[Nn * 64 + i] = 0; }
}

__global__ void k_edge_pre(const int* __restrict__ col, const float* __restrict__ ew,
                           float* __restrict__ deg, int* __restrict__ cnt, int E) {
  int e = blockIdx.x * 256 + threadIdx.x;
  if (e < E) { int c = col[e]; atomicAdd(&deg[c], ew[e]); atomicAdd(&cnt[c], 1); }
}

__global__ void k_dis(float* __restrict__ deg, int n) {
  int i = blockIdx.x * 256 + threadIdx.x;
  if (i < n) { float d = deg[i]; deg[i] = (d > 0.0f) ? rsqrtf(d) : 0.0f; }
}

// single-block exclusive scan of cnt[0..n) -> ofs[0..n], plus copy into ofs2
__global__ __launch_bounds__(256) void k_scan(const int* __restrict__ cnt,
                                              int* __restrict__ ofs, int* __restrict__ ofs2,
                                              int n) {
  __shared__ int partial[256];
  const int t = threadIdx.x;
  const int CH = (n + 255) / 256;
  const int start = t * CH;
  int local = 0;
  for (int j = 0; j < CH; ++j) {
    int idx = start + j;
    if (idx < n) local += cnt[idx];
  }
  partial[t] = local;
  __syncthreads();
  for (int off = 1; off < 256; off <<= 1) {
    int x = (t >= off) ? partial[t - off] : 0;
    __syncthreads();
    partial[t] += x;
    __syncthreads();
  }
  int run = partial[t] - local;  // exclusive prefix
  for (int j = 0; j < CH; ++j) {
    int idx = start + j;
    if (idx < n) {
      ofs[idx] = run; ofs2[idx] = run;
      run += cnt[idx];
    }
  }
  if (t == 255) { ofs[n] = run; ofs2[n] = run; }
}

// place edges: csr_src[p]=row, csr_w[p]=dis[row]*ew*dis[col]
__global__ void k_fill(const int* __restrict__ row, const int* __restrict__ col,
                       const float* __restrict__ ew, const float* __restrict__ dis,
                       int* __restrict__ ofs2, int* __restrict__ csr_src,
                       float* __restrict__ csr_w, int E) {
  int e = blockIdx.x * 256 + threadIdx.x;
  if (e < E) {
    int r = row[e], c = col[e];
    int p = atomicAdd(&ofs2[c], 1);
    csr_src[p] = r;
    csr_w[p] = dis[r] * ew[e] * dis[c];
  }
}

// hw1 = x[10000,256] @ W1[256,128]
__global__ __launch_bounds__(256) void k_gemm1(const float* __restrict__ x,
                                               const float* __restrict__ W1,
                                               float* __restrict__ hw1) {
  __shared__ float xs[16][68];
  __shared__ float ws[64][128];
  const int tid = threadIdx.x;
  const int row0 = blockIdx.x * 16;
  const int j0 = (tid & 31) * 4;
  const int r0 = (tid >> 5) * 2;
  const int lr = tid >> 4, lk = tid & 15;
  float acc0[4] = {0, 0, 0, 0}, acc1[4] = {0, 0, 0, 0};
  for (int k0 = 0; k0 < 256; k0 += 64) {
    *(float4*)&xs[lr][lk * 4] = *(const float4*)&x[(row0 + lr) * 256 + k0 + lk * 4];
#pragma unroll
    for (int it = 0; it < 8; ++it) {
      int idx4 = tid + it * 256;
      int kk = idx4 >> 5, jq = idx4 & 31;
      *(float4*)&ws[kk][jq * 4] = *(const float4*)&W1[(k0 + kk) * 128 + jq * 4];
    }
    __syncthreads();
#pragma unroll 8
    for (int kk = 0; kk < 64; ++kk) {
      float a0 = xs[r0][kk], a1 = xs[r0 + 1][kk];
      float4 w = *(const float4*)&ws[kk][j0];
      acc0[0] += a0 * w.x; acc0[1] += a0 * w.y; acc0[2] += a0 * w.z; acc0[3] += a0 * w.w;
      acc1[0] += a1 * w.x; acc1[1] += a1 * w.y; acc1[2] += a1 * w.z; acc1[3] += a1 * w.w;
    }
    __syncthreads();
  }
  *(float4*)&hw1[(row0 + r0) * 128 + j0] = make_float4(acc0[0], acc0[1], acc0[2], acc0[3]);
  *(float4*)&hw1[(row0 + r0 + 1) * 128 + j0] = make_float4(acc1[0], acc1[1], acc1[2], acc1[3]);
}

// CSR aggregation, 4 nodes/block (1 wave each), float2 per lane.
// mode 0: out[i] = relu(d^2*feat[i] + b + sum w*feat[src])   (conv1 output)
// mode 1: out[i] = d^2*feat[i] + sum w*feat[src]             (pre-GEMM agg)
__global__ __launch_bounds__(256) void k_agg(const int* __restrict__ ofs,
                                             const int* __restrict__ csr_src,
                                             const float* __restrict__ csr_w,
                                             const float* __restrict__ feat,
                                             const float* __restrict__ dis,
                                             const float* __restrict__ b,
                                             float* __restrict__ out, int n, int mode) {
  int node = blockIdx.x * 4 + (threadIdx.x >> 6);
  if (node >= n) return;
  int f2 = threadIdx.x & 63;
  const float2* featv = (const float2*)feat;
  int s = ofs[node], e = ofs[node + 1];
  float d = dis[node];
  float2 self = featv[node * 64 + f2];
  float accx = d * d * self.x, accy = d * d * self.y;
  int j = s;
  for (; j + 2 <= e; j += 2) {   // 2-deep: both gathers in flight before use
    int r0 = csr_src[j], r1 = csr_src[j + 1];
    float w0 = csr_w[j], w1 = csr_w[j + 1];
    float2 v0 = featv[r0 * 64 + f2];
    float2 v1 = featv[r1 * 64 + f2];
    accx += w0 * v0.x + w1 * v1.x;
    accy += w0 * v0.y + w1 * v1.y;
  }
  if (j < e) {
    int r0 = csr_src[j];
    float w0 = csr_w[j];
    float2 v0 = featv[r0 * 64 + f2];
    accx += w0 * v0.x;
    accy += w0 * v0.y;
  }
  float2 o;
  if (mode == 0) {
    float2 bb = ((const float2*)b)[f2];
    o.x = fmaxf(accx + bb.x, 0.0f);
    o.y = fmaxf(accy + bb.y, 0.0f);
  } else {
    o.x = accx; o.y = accy;
  }
  ((float2*)out)[node * 64 + f2] = o;
}

// Fused: [mean|lstd] = hagg[10000,128] @ [W2|W3][128,64] + [b2|b3], then
// z = mean + noise*exp(lstd), bf16 hi/lo split written straight to zh/zl.
__global__ __launch_bounds__(256) void k_gemm2z(const float* __restrict__ hagg,
                                                const float* __restrict__ W2, const float* __restrict__ W3,
                                                const float* __restrict__ b2, const float* __restrict__ b3,
                                                const float* __restrict__ noise,
                                                unsigned short* __restrict__ zh,
                                                unsigned short* __restrict__ zl) {
  __shared__ float xs[16][68];
  __shared__ float ws[64][128];
  __shared__ float zs[16][128];   // [mean | lstd] staging for the fusion
  const int tid = threadIdx.x;
  const int row0 = blockIdx.x * 16;
  const int j0 = (tid & 31) * 4;
  const int r0 = (tid >> 5) * 2;
  const int lr = tid >> 4, lk = tid & 15;
  float acc0[4] = {0, 0, 0, 0}, acc1[4] = {0, 0, 0, 0};
  for (int k0 = 0; k0 < 128; k0 += 64) {
    *(float4*)&xs[lr][lk * 4] = *(const float4*)&hagg[(row0 + lr) * 128 + k0 + lk * 4];
#pragma unroll
    for (int it = 0; it < 8; ++it) {
      int idx4 = tid + it * 256;
      int kk = idx4 >> 5, jq = idx4 & 31;
      int j = jq * 4;
      float4 wv;
      if (j < 64) wv = *(const float4*)&W2[(k0 + kk) * 64 + j];
      else        wv = *(const float4*)&W3[(k0 + kk) * 64 + (j - 64)];
      *(float4*)&ws[kk][j] = wv;
    }
    __syncthreads();
#pragma unroll 8
    for (int kk = 0; kk < 64; ++kk) {
      float a0 = xs[r0][kk], a1 = xs[r0 + 1][kk];
      float4 w = *(const float4*)&ws[kk][j0];
      acc0[0] += a0 * w.x; acc0[1] += a0 * w.y; acc0[2] += a0 * w.z; acc0[3] += a0 * w.w;
      acc1[0] += a1 * w.x; acc1[1] += a1 * w.y; acc1[2] += a1 * w.z; acc1[3] += a1 * w.w;
    }
    __syncthreads();
  }
  {
    float4 bb = (j0 < 64) ? *(const float4*)&b2[j0] : *(const float4*)&b3[j0 - 64];
    zs[r0][j0 + 0] = acc0[0] + bb.x; zs[r0][j0 + 1] = acc0[1] + bb.y;
    zs[r0][j0 + 2] = acc0[2] + bb.z; zs[r0][j0 + 3] = acc0[3] + bb.w;
    zs[r0 + 1][j0 + 0] = acc1[0] + bb.x; zs[r0 + 1][j0 + 1] = acc1[1] + bb.y;
    zs[r0 + 1][j0 + 2] = acc1[2] + bb.z; zs[r0 + 1][j0 + 3] = acc1[3] + bb.w;
  }
  __syncthreads();
  {
    const int r = tid >> 4;
    const int jj = (tid & 15) * 4;
    float4 mn = *(const float4*)&zs[r][jj];
    float4 ls = *(const float4*)&zs[r][64 + jj];
    float4 nz = *(const float4*)&noise[(row0 + r) * 64 + jj];
    float z0 = mn.x + nz.x * __expf(ls.x);
    float z1 = mn.y + nz.y * __expf(ls.y);
    float z2 = mn.z + nz.z * __expf(ls.z);
    float z3 = mn.w + nz.w * __expf(ls.w);
    ushort4e h, l;
    h[0] = f32_to_bf16(z0); l[0] = f32_to_bf16(z0 - bf16_to_f32(h[0]));
    h[1] = f32_to_bf16(z1); l[1] = f32_to_bf16(z1 - bf16_to_f32(h[1]));
    h[2] = f32_to_bf16(z2); l[2] = f32_to_bf16(z2 - bf16_to_f32(h[2]));
    h[3] = f32_to_bf16(z3); l[3] = f32_to_bf16(z3 - bf16_to_f32(h[3]));
    *(ushort4e*)&zh[(row0 + r) * 64 + jj] = h;
    *(ushort4e*)&zl[(row0 + r) * 64 + jj] = l;
  }
}

// out = sigmoid(z@z^T), 128x128 tile / 4 waves, each wave 64x64.
// zh/zl row+col tiles staged once per block in LDS (64 KB), XOR-swizzled
// (16B chunk index ^= row&7) so the stride-128B ds_read_b128 fragment reads
// are 2-way (free). Operand-swapped MFMA -> lane holds 4 consecutive cols of
// one row -> f32x4 stores; regular (cached) stores so L2 merges the 64 B
// row-segments of adjacent store instructions into full lines.
__global__ __launch_bounds__(256) void k_decode(const unsigned short* __restrict__ zh,
                                                const unsigned short* __restrict__ zl,
                                                float* __restrict__ out, int n) {
  __shared__ short zhr[128][64];
  __shared__ short zlr[128][64];
  __shared__ short zhc[128][64];
  __shared__ short zlc[128][64];
  const int tid = threadIdx.x;
  const int R0 = blockIdx.y * 128;
  const int C0 = blockIdx.x * 128;

  // stage: 4 arrays x 128 rows x 128 B; thread -> (row tid>>3, 16B seg tid&7)
  {
    const int seg = tid & 7;
#pragma unroll
    for (int p = 0; p < 4; ++p) {
      const int rr = (p << 5) + (tid >> 3);
      const int sw = (seg ^ (rr & 7)) * 8;
      short8 vhr = *(const short8*)&zh[(size_t)(R0 + rr) * 64 + seg * 8];
      short8 vlr = *(const short8*)&zl[(size_t)(R0 + rr) * 64 + seg * 8];
      short8 vhc = *(const short8*)&zh[(size_t)(C0 + rr) * 64 + seg * 8];
      short8 vlc = *(const short8*)&zl[(size_t)(C0 + rr) * 64 + seg * 8];
      *(short8*)&zhr[rr][sw] = vhr;
      *(short8*)&zlr[rr][sw] = vlr;
      *(short8*)&zhc[rr][sw] = vhc;
      *(short8*)&zlc[rr][sw] = vlc;
    }
  }
  __syncthreads();

  const int wave = tid >> 6, lane = tid & 63;
  const int lr0 = (wave >> 1) * 64;   // wave row base within tile
  const int lc0 = (wave & 1) * 64;    // wave col base within tile
  const int lrow = lane & 15;
  const int quad = lane >> 4;
  f32x4 acc[4][4];
#pragma unroll
  for (int m = 0; m < 4; ++m)
#pragma unroll
    for (int nn = 0; nn < 4; ++nn) acc[m][nn] = (f32x4){0.0f, 0.0f, 0.0f, 0.0f};

#pragma unroll
  for (int kc = 0; kc < 64; kc += 32) {
    const int cb = (kc >> 3) + quad;   // 16B chunk index within row (0..7)
    short8 rh[4], rl[4], ch[4], cl[4];
#pragma unroll
    for (int m = 0; m < 4; ++m) {
      int row = lr0 + m * 16 + lrow;
      int sw = (cb ^ (row & 7)) * 8;
      rh[m] = *(const short8*)&zhr[row][sw];
      rl[m] = *(const short8*)&zlr[row][sw];
    }
#pragma unroll
    for (int nn = 0; nn < 4; ++nn) {
      int row = lc0 + nn * 16 + lrow;
      int sw = (cb ^ (row & 7)) * 8;
      ch[nn] = *(const short8*)&zhc[row][sw];
      cl[nn] = *(const short8*)&zlc[row][sw];
    }
#pragma unroll
    for (int m = 0; m < 4; ++m)
#pragma unroll
      for (int nn = 0; nn < 4; ++nn) {
        acc[m][nn] = __builtin_amdgcn_mfma_f32_16x16x32_bf16(ch[nn], rh[m], acc[m][nn], 0, 0, 0);
        acc[m][nn] = __builtin_amdgcn_mfma_f32_16x16x32_bf16(cl[nn], rh[m], acc[m][nn], 0, 0, 0);
        acc[m][nn] = __builtin_amdgcn_mfma_f32_16x16x32_bf16(ch[nn], rl[m], acc[m][nn], 0, 0, 0);
      }
  }

  // transposed C layout: lane holds row (R0+lr0+m*16+lrow), cols quad*4+r
#pragma unroll
  for (int m = 0; m < 4; ++m) {
    int gr = R0 + lr0 + m * 16 + lrow;
    if (gr >= n) continue;
#pragma unroll
    for (int nn = 0; nn < 4; ++nn) {
      int c0 = C0 + lc0 + nn * 16 + quad * 4;
      if (c0 >= n) continue;  // n % 4 == 0 -> chunk fully in or out
      f32x4 v;
      v[0] = sigmoidf(acc[m][nn][0]);
      v[1] = sigmoidf(acc[m][nn][1]);
      v[2] = sigmoidf(acc[m][nn][2]);
      v[3] = sigmoidf(acc[m][nn][3]);
      *(f32x4*)&out[(size_t)gr * n + c0] = v;
    }
  }
}

extern "C" void kernel_launch(void* const* d_in, const int* in_sizes, int n_in,
                              void* d_out, int out_size, void* d_ws, size_t ws_size,
                              hipStream_t stream) {
  const float* x     = (const float*)d_in[0];
  const int*   ei    = (const int*)d_in[1];
  const float* ew    = (const float*)d_in[2];
  const float* noise = (const float*)d_in[3];
  const float* W1    = (const float*)d_in[4];
  const float* b1    = (const float*)d_in[5];
  const float* W2    = (const float*)d_in[6];
  const float* b2    = (const float*)d_in[7];
  const float* W3    = (const float*)d_in[8];
  const float* b3    = (const float*)d_in[9];
  const int E = in_sizes[2];
  const int n = Nn;
  const int* row = ei;
  const int* col = ei + E;

  // d_ws: dis (40 KB) + zh + zl (2.6 MB)
  float* dis = (float*)d_ws;
  unsigned short* zh = (unsigned short*)((char*)d_ws + 10240 * 4);
  unsigned short* zl = zh + NpK;

  // big scratch in d_out (all dead before k_decode rewrites d_out)
  float* S    = (float*)d_out;
  float* hw1  = S;                         // n*128
  float* h    = S + 1310720;               // n*128
  float* hagg = S + 2621440;               // n*128
  float* csr_w  = S + 5242880;             // E
  int* csr_src  = (int*)(S + 5402880);     // E
  int* ofs      = (int*)(S + 5562880);     // n+1
  int* ofs2     = (int*)(S + 5572896);     // n+1
  int* cnt      = (int*)(S + 5582912);     // n

  k_init<<<(n + 255) / 256, 256, 0, stream>>>(dis, cnt, n, zh, zl);
  k_edge_pre<<<(E + 255) / 256, 256, 0, stream>>>(col, ew, dis, cnt, E);
  k_dis<<<(n + 255) / 256, 256, 0, stream>>>(dis, n);
  k_scan<<<1, 256, 0, stream>>>(cnt, ofs, ofs2, n);
  k_fill<<<(E + 255) / 256, 256, 0, stream>>>(row, col, ew, dis, ofs2, csr_src, csr_w, E);

  k_gemm1<<<n / 16, 256, 0, stream>>>(x, W1, hw1);
  k_agg<<<(n + 3) / 4, 256, 0, stream>>>(ofs, csr_src, csr_w, hw1, dis, b1, h, n, 0);
  k_agg<<<(n + 3) / 4, 256, 0, stream>>>(ofs, csr_src, csr_w, h, dis, b1, hagg, n, 1);

  k_gemm2z<<<n / 16, 256, 0, stream>>>(hagg, W2, W3, b2, b3, noise, zh, zl);

  dim3 g((n + 127) / 128, (n + 127) / 128);
  k_decode<<<g, 256, 0, stream>>>(zh, zl, (float*)d_out, n);
}